// Round 1
// baseline (207.705 us; speedup 1.0000x reference)
//
#include <hip/hip_runtime.h>
#include <math.h>

// Workspace layout (floats)
#define WS_W0 0
#define WS_W1 4096
#define WS_W2 (4096 + 262144)
#define WS_W3 (4096 + 262144 + 131072)
// total 462848 floats = 1.85 MB

// ---------------- prep: weight-normalize v -> w into ws ----------------
__global__ void prep_weights(const float* __restrict__ v0, const float* __restrict__ g0,
                             const float* __restrict__ v1, const float* __restrict__ g1,
                             const float* __restrict__ v2, const float* __restrict__ g2,
                             const float* __restrict__ v3, const float* __restrict__ g3,
                             float* __restrict__ ws) {
    int t = blockIdx.x * blockDim.x + threadIdx.x;
    if (t < 4096) {
        // w0[f][o] = g0 * v0 / |v0|   (norm over a length-1 axis)
        float v = v0[t];
        ws[WS_W0 + t] = g0[t] * v / fabsf(v);
    } else if (t < 8192) {
        int r = t - 4096;                       // r = f*64 + o
        const float* vp = v1 + (size_t)r * 64;
        float ss = 0.f;
        #pragma unroll
        for (int i = 0; i < 64; ++i) ss += vp[i] * vp[i];
        float scale = g1[r] / sqrtf(ss);
        float* wp = ws + WS_W1 + (size_t)r * 64;
        #pragma unroll
        for (int i = 0; i < 64; ++i) wp[i] = vp[i] * scale;
    } else if (t < 10240) {
        int r = t - 8192;                       // r = f*32 + o
        const float* vp = v2 + (size_t)r * 64;
        float ss = 0.f;
        #pragma unroll
        for (int i = 0; i < 64; ++i) ss += vp[i] * vp[i];
        float scale = g2[r] / sqrtf(ss);
        float* wp = ws + WS_W2 + (size_t)r * 64;
        #pragma unroll
        for (int i = 0; i < 64; ++i) wp[i] = vp[i] * scale;
    } else if (t < 12288) {
        int r = t - 10240;                      // r = f*32 + o
        const float* vp = v3 + (size_t)r * 32;
        float ss = 0.f;
        #pragma unroll
        for (int i = 0; i < 32; ++i) ss += vp[i] * vp[i];
        float scale = g3[r] / sqrtf(ss);
        float* wp = ws + WS_W3 + (size_t)r * 32;
        #pragma unroll
        for (int i = 0; i < 32; ++i) wp[i] = vp[i] * scale;
    }
}

// ---------------- real features: per-feature MLP ----------------
// grid: (64 features, 32 batch tiles), block: 256 threads (1 batch elem each)
__global__ __launch_bounds__(256)
void nam_real(const float* __restrict__ tab, const float* __restrict__ ws,
              const float* __restrict__ b0, const float* __restrict__ b1,
              const float* __restrict__ b2, const float* __restrict__ memb,
              float* __restrict__ feat) {
    const int f = blockIdx.x;                       // wave-uniform
    const int b = blockIdx.y * 256 + threadIdx.x;

    const float val  = tab[(size_t)b * 192 + f];
    const float miss = tab[(size_t)b * 192 + 96 + f];

    const float* __restrict__ w0  = ws + WS_W0 + f * 64;
    const float* __restrict__ w1  = ws + WS_W1 + f * 4096;
    const float* __restrict__ w2  = ws + WS_W2 + f * 2048;
    const float* __restrict__ w3  = ws + WS_W3 + f * 1024;
    const float* __restrict__ bb0 = b0 + f * 64;
    const float* __restrict__ bb1 = b1 + f * 64;
    const float* __restrict__ bb2 = b2 + f * 32;

    float h0[64];
    #pragma unroll
    for (int o = 0; o < 64; ++o)
        h0[o] = fmaxf(fmaf(val, w0[o], bb0[o]), 0.f);

    float h1[64];
    #pragma unroll
    for (int o = 0; o < 64; ++o) {
        float acc = bb1[o];
        #pragma unroll
        for (int i = 0; i < 64; ++i) acc = fmaf(h0[i], w1[o * 64 + i], acc);
        h1[o] = fmaxf(acc, 0.f);
    }

    float h2[32];
    #pragma unroll
    for (int o = 0; o < 32; ++o) {
        float acc = bb2[o];
        #pragma unroll
        for (int i = 0; i < 64; ++i) acc = fmaf(h1[i], w2[o * 64 + i], acc);
        h2[o] = fmaxf(acc, 0.f);
    }

    float o3[32];
    #pragma unroll
    for (int o = 0; o < 32; ++o) {
        float acc = 0.f;
        #pragma unroll
        for (int i = 0; i < 32; ++i) acc = fmaf(h2[i], w3[o * 32 + i], acc);
        o3[o] = acc;
    }

    const float keep = 1.f - miss;
    float* dst = feat + (size_t)b * 3072 + f * 32;
    if (f < 16) {
        const float* e = memb + (8 + f) * 32;
        #pragma unroll
        for (int o = 0; o < 32; ++o)
            dst[o] = fmaf(e[o], miss, o3[o] * keep);
    } else {
        #pragma unroll
        for (int o = 0; o < 32; ++o)
            dst[o] = o3[o] * keep;
    }
}

// ---------------- categorical features ----------------
__global__ __launch_bounds__(256)
void nam_cat(const float* __restrict__ tab, const float* __restrict__ cat_linear,
             const float* __restrict__ memb, float* __restrict__ feat) {
    int t = blockIdx.x * blockDim.x + threadIdx.x;   // 8192*32*32 threads
    int o  = t & 31;
    int fc = (t >> 5) & 31;
    int b  = t >> 10;
    float val  = tab[(size_t)b * 192 + 64 + fc];
    float miss = tab[(size_t)b * 192 + 96 + 64 + fc];
    float r = cat_linear[fc * 32 + o] * val * (1.f - miss);
    if (fc < 8) r = fmaf(memb[fc * 32 + o], miss, r);
    feat[(size_t)b * 3072 + (64 + fc) * 32 + o] = r;
}

// ---------------- logits: sum over 96 features + bias ----------------
__global__ __launch_bounds__(256)
void nam_logits(const float* __restrict__ feat, const float* __restrict__ bias,
                float* __restrict__ logits) {
    int t = blockIdx.x * blockDim.x + threadIdx.x;   // 8192*32 threads
    int o = t & 31;
    int b = t >> 5;
    float s = bias[o];
    const float* fp = feat + (size_t)b * 3072 + o;
    #pragma unroll 8
    for (int f = 0; f < 96; ++f) s += fp[f * 32];
    logits[t] = s;
}

extern "C" void kernel_launch(void* const* d_in, const int* in_sizes, int n_in,
                              void* d_out, int out_size, void* d_ws, size_t ws_size,
                              hipStream_t stream) {
    const float* tab        = (const float*)d_in[0];
    const float* v0         = (const float*)d_in[1];
    const float* g0         = (const float*)d_in[2];
    const float* b0         = (const float*)d_in[3];
    const float* v1         = (const float*)d_in[4];
    const float* g1         = (const float*)d_in[5];
    const float* b1         = (const float*)d_in[6];
    const float* v2         = (const float*)d_in[7];
    const float* g2         = (const float*)d_in[8];
    const float* b2         = (const float*)d_in[9];
    const float* v3         = (const float*)d_in[10];
    const float* g3         = (const float*)d_in[11];
    const float* cat_linear = (const float*)d_in[12];
    const float* memb       = (const float*)d_in[13];
    const float* bias       = (const float*)d_in[14];

    float* out    = (float*)d_out;
    float* logits = out;                    // 8192*32
    float* feat   = out + 8192 * 32;        // 8192*96*32
    float* ws     = (float*)d_ws;

    // 1) weight-norm prep (12288 row tasks)
    prep_weights<<<48, 256, 0, stream>>>(v0, g0, v1, g1, v2, g2, v3, g3, ws);

    // 2) real-feature MLPs
    dim3 gr(64, 32);
    nam_real<<<gr, 256, 0, stream>>>(tab, ws, b0, b1, b2, memb, feat);

    // 3) categorical features
    nam_cat<<<(8192 * 32 * 32) / 256, 256, 0, stream>>>(tab, cat_linear, memb, feat);

    // 4) logits reduction
    nam_logits<<<(8192 * 32) / 256, 256, 0, stream>>>(feat, bias, logits);
}

// Round 2
// 53.047 us; speedup vs baseline: 3.9155x; 3.9155x over previous
//
#include <hip/hip_runtime.h>
#include <math.h>

typedef _Float16 f16;
typedef _Float16 f16x8 __attribute__((ext_vector_type(8)));
typedef float f32x4 __attribute__((ext_vector_type(4)));

#define NB 8192
#define LOGN (NB * 32)          // 262144 logits elements

// ---- ws byte layout ----
// [0, 16384)              W0 fp32 (64f x 64)  (= g0 * sign(v0))
// [16384, +524288)        B1 fragments fp16: [f][ks(2)][nt(4)][lane(64)][8]
// [540672, +262144)       B2 fragments fp16: [f][ks(2)][nt(2)][lane][8]
// [802816, +131072)       B3 fragments fp16: [f][ks(1)][nt(2)][lane][8]
// [933888, +9*LOGN*4)     partial logits: 9 planes of [8192][32] fp32
#define OFF_B1 16384
#define OFF_B2 540672
#define OFF_B3 802816
#define OFF_PART 933888

// ---------------- prep: weight-norm -> fp16 MFMA B-fragments ----------------
__global__ void prep_weights(const float* __restrict__ v0, const float* __restrict__ g0,
                             const float* __restrict__ v1, const float* __restrict__ g1,
                             const float* __restrict__ v2, const float* __restrict__ g2,
                             const float* __restrict__ v3, const float* __restrict__ g3,
                             float* __restrict__ w0, f16* __restrict__ b1f,
                             f16* __restrict__ b2f, f16* __restrict__ b3f) {
    int t = blockIdx.x * blockDim.x + threadIdx.x;
    if (t < 4096) {
        // norm over length-1 axis: w = g * sign(v)
        float v = v0[t];
        w0[t] = g0[t] * (v >= 0.f ? 1.f : -1.f);
    } else if (t < 8192) {
        int r = t - 4096;                // r = f*64 + n
        int f = r >> 6, n = r & 63;
        const float* vp = v1 + (size_t)r * 64;
        float ss = 0.f;
        #pragma unroll
        for (int i = 0; i < 64; ++i) ss += vp[i] * vp[i];
        float scale = g1[r] * __frsqrt_rn(ss);
        f16* dst = b1f + f * 4096;
        #pragma unroll
        for (int k = 0; k < 64; ++k) {
            int lane = (n & 15) | (((k & 31) >> 3) << 4);
            dst[(k >> 5) * 2048 + (n >> 4) * 512 + lane * 8 + (k & 7)] = (f16)(vp[k] * scale);
        }
    } else if (t < 10240) {
        int r = t - 8192;                // r = f*32 + n
        int f = r >> 5, n = r & 31;
        const float* vp = v2 + (size_t)r * 64;
        float ss = 0.f;
        #pragma unroll
        for (int i = 0; i < 64; ++i) ss += vp[i] * vp[i];
        float scale = g2[r] * __frsqrt_rn(ss);
        f16* dst = b2f + f * 2048;
        #pragma unroll
        for (int k = 0; k < 64; ++k) {
            int lane = (n & 15) | (((k & 31) >> 3) << 4);
            dst[(k >> 5) * 1024 + (n >> 4) * 512 + lane * 8 + (k & 7)] = (f16)(vp[k] * scale);
        }
    } else if (t < 12288) {
        int r = t - 10240;               // r = f*32 + n
        int f = r >> 5, n = r & 31;
        const float* vp = v3 + (size_t)r * 32;
        float ss = 0.f;
        #pragma unroll
        for (int i = 0; i < 32; ++i) ss += vp[i] * vp[i];
        float scale = g3[r] * __frsqrt_rn(ss);
        f16* dst = b3f + f * 1024;
        #pragma unroll
        for (int k = 0; k < 32; ++k) {
            int lane = (n & 15) | ((k >> 3) << 4);
            dst[(n >> 4) * 512 + lane * 8 + (k & 7)] = (f16)(vp[k] * scale);
        }
    }
}

// ---------------- real features: MFMA MLP chain ----------------
// grid (64 batch-tiles, 8 feature-groups) x 256 thr. Wave-private: 32 rows/wave, 8 features.
__global__ __launch_bounds__(256, 2)
void nam_real_mfma(const float* __restrict__ tab, const float* __restrict__ w0,
                   const f16* __restrict__ b1f, const f16* __restrict__ b2f,
                   const f16* __restrict__ b3f,
                   const float* __restrict__ b0, const float* __restrict__ b1,
                   const float* __restrict__ b2, const float* __restrict__ memb,
                   float* __restrict__ feat, float* __restrict__ part) {
    __shared__ char lds[4][8192];
    const int wave = threadIdx.x >> 6, lane = threadIdx.x & 63;
    const int lq = lane >> 4, lr = lane & 15;      // D: col=lr, rows=lq*4+j ; A: row=lr, k=lq*8+i
    const int rowbase = blockIdx.x * 128 + wave * 32;
    const int f0 = blockIdx.y * 8;
    char* h1b = lds[wave];            // 32 rows x 128B, XOR-swizzled
    char* h2b = lds[wave] + 4096;     // 32 rows x 128B, XOR-swizzled

    float lacc[2][2][4];
    #pragma unroll
    for (int mt = 0; mt < 2; ++mt)
        #pragma unroll
        for (int nt = 0; nt < 2; ++nt)
            #pragma unroll
            for (int j = 0; j < 4; ++j) lacc[mt][nt][j] = 0.f;

    #pragma unroll 1
    for (int fi = 0; fi < 8; ++fi) {
        const int f = f0 + fi;

        // ---- B fragments (coalesced 16B/lane, L2-resident) ----
        f16x8 B1[2][4], B2[2][2], B3[2];
        {
            const f16* p1 = b1f + f * 4096 + lane * 8;
            #pragma unroll
            for (int ks = 0; ks < 2; ++ks)
                #pragma unroll
                for (int nt = 0; nt < 4; ++nt)
                    B1[ks][nt] = *(const f16x8*)(p1 + ks * 2048 + nt * 512);
            const f16* p2 = b2f + f * 2048 + lane * 8;
            #pragma unroll
            for (int ks = 0; ks < 2; ++ks)
                #pragma unroll
                for (int nt = 0; nt < 2; ++nt)
                    B2[ks][nt] = *(const f16x8*)(p2 + ks * 1024 + nt * 512);
            const f16* p3 = b3f + f * 1024 + lane * 8;
            #pragma unroll
            for (int nt = 0; nt < 2; ++nt)
                B3[nt] = *(const f16x8*)(p3 + nt * 512);
        }

        // ---- biases / per-row inputs ----
        float b1v[4], b2v[2];
        #pragma unroll
        for (int nt = 0; nt < 4; ++nt) b1v[nt] = b1[f * 64 + nt * 16 + lr];
        #pragma unroll
        for (int nt = 0; nt < 2; ++nt) b2v[nt] = b2[f * 32 + nt * 16 + lr];
        float vmt[2];
        #pragma unroll
        for (int mt = 0; mt < 2; ++mt)
            vmt[mt] = tab[(size_t)(rowbase + mt * 16 + lr) * 192 + f];
        float ms[2][4];
        #pragma unroll
        for (int mt = 0; mt < 2; ++mt)
            #pragma unroll
            for (int j = 0; j < 4; ++j)
                ms[mt][j] = tab[(size_t)(rowbase + mt * 16 + lq * 4 + j) * 192 + 96 + f];

        // ---- layer 0: build A fragments in registers (w0 = +/- g0) ----
        f16x8 A0[2][2];
        #pragma unroll
        for (int ks = 0; ks < 2; ++ks) {
            float w0v[8], b0v[8];
            *(float4*)&w0v[0] = *(const float4*)(w0 + f * 64 + ks * 32 + lq * 8);
            *(float4*)&w0v[4] = *(const float4*)(w0 + f * 64 + ks * 32 + lq * 8 + 4);
            *(float4*)&b0v[0] = *(const float4*)(b0 + f * 64 + ks * 32 + lq * 8);
            *(float4*)&b0v[4] = *(const float4*)(b0 + f * 64 + ks * 32 + lq * 8 + 4);
            #pragma unroll
            for (int mt = 0; mt < 2; ++mt)
                #pragma unroll
                for (int i = 0; i < 8; ++i)
                    A0[mt][ks][i] = (f16)fmaxf(fmaf(vmt[mt], w0v[i], b0v[i]), 0.f);
        }

        // ---- layer 1: [32x64] = A0[32x64] * W1^T ----
        f32x4 acc1[2][4];
        #pragma unroll
        for (int mt = 0; mt < 2; ++mt)
            #pragma unroll
            for (int nt = 0; nt < 4; ++nt) acc1[mt][nt] = (f32x4){0.f, 0.f, 0.f, 0.f};
        #pragma unroll
        for (int ks = 0; ks < 2; ++ks)
            #pragma unroll
            for (int nt = 0; nt < 4; ++nt)
                #pragma unroll
                for (int mt = 0; mt < 2; ++mt)
                    acc1[mt][nt] = __builtin_amdgcn_mfma_f32_16x16x32_f16(A0[mt][ks], B1[ks][nt], acc1[mt][nt], 0, 0, 0);
        // relu+bias -> fp16 -> swizzled LDS  (value (row,n): byte = row*128 + (n>>3)*16 + (n&7)*2 ^ (row&7)<<4)
        #pragma unroll
        for (int mt = 0; mt < 2; ++mt)
            #pragma unroll
            for (int nt = 0; nt < 4; ++nt) {
                int n = nt * 16 + lr;
                int colb = ((n >> 3) << 4) + ((n & 7) << 1);
                #pragma unroll
                for (int j = 0; j < 4; ++j) {
                    int row = mt * 16 + lq * 4 + j;
                    int byte = ((row << 7) + colb) ^ ((row & 7) << 4);
                    *(f16*)(h1b + byte) = (f16)fmaxf(acc1[mt][nt][j] + b1v[nt], 0.f);
                }
            }

        // ---- layer 2: [32x32] = H1[32x64] * W2^T ----
        f16x8 A1[2][2];
        #pragma unroll
        for (int mt = 0; mt < 2; ++mt)
            #pragma unroll
            for (int ks = 0; ks < 2; ++ks) {
                int row = mt * 16 + lr;
                int byte = ((row << 7) + ((ks * 4 + lq) << 4)) ^ ((row & 7) << 4);
                A1[mt][ks] = *(const f16x8*)(h1b + byte);
            }
        f32x4 acc2[2][2];
        #pragma unroll
        for (int mt = 0; mt < 2; ++mt)
            #pragma unroll
            for (int nt = 0; nt < 2; ++nt) acc2[mt][nt] = (f32x4){0.f, 0.f, 0.f, 0.f};
        #pragma unroll
        for (int ks = 0; ks < 2; ++ks)
            #pragma unroll
            for (int nt = 0; nt < 2; ++nt)
                #pragma unroll
                for (int mt = 0; mt < 2; ++mt)
                    acc2[mt][nt] = __builtin_amdgcn_mfma_f32_16x16x32_f16(A1[mt][ks], B2[ks][nt], acc2[mt][nt], 0, 0, 0);
        #pragma unroll
        for (int mt = 0; mt < 2; ++mt)
            #pragma unroll
            for (int nt = 0; nt < 2; ++nt) {
                int n = nt * 16 + lr;
                int colb = ((n >> 3) << 4) + ((n & 7) << 1);
                #pragma unroll
                for (int j = 0; j < 4; ++j) {
                    int row = mt * 16 + lq * 4 + j;
                    int byte = ((row << 7) + colb) ^ ((row & 7) << 4);
                    *(f16*)(h2b + byte) = (f16)fmaxf(acc2[mt][nt][j] + b2v[nt], 0.f);
                }
            }

        // ---- layer 3: [32x32] = H2[32x32] * W3^T (no relu/bias) ----
        f16x8 A2[2];
        #pragma unroll
        for (int mt = 0; mt < 2; ++mt) {
            int row = mt * 16 + lr;
            int byte = ((row << 7) + (lq << 4)) ^ ((row & 7) << 4);
            A2[mt] = *(const f16x8*)(h2b + byte);
        }
        f32x4 acc3[2][2];
        #pragma unroll
        for (int mt = 0; mt < 2; ++mt)
            #pragma unroll
            for (int nt = 0; nt < 2; ++nt) acc3[mt][nt] = (f32x4){0.f, 0.f, 0.f, 0.f};
        #pragma unroll
        for (int nt = 0; nt < 2; ++nt)
            #pragma unroll
            for (int mt = 0; mt < 2; ++mt)
                acc3[mt][nt] = __builtin_amdgcn_mfma_f32_16x16x32_f16(A2[mt], B3[nt], acc3[mt][nt], 0, 0, 0);

        // ---- epilogue: mask, missing-emb, store, logits partial ----
        float e[2] = {0.f, 0.f};
        const bool hasemb = (f < 16);
        if (hasemb) {
            #pragma unroll
            for (int nt = 0; nt < 2; ++nt) e[nt] = memb[(8 + f) * 32 + nt * 16 + lr];
        }
        #pragma unroll
        for (int mt = 0; mt < 2; ++mt)
            #pragma unroll
            for (int nt = 0; nt < 2; ++nt) {
                int o = nt * 16 + lr;
                #pragma unroll
                for (int j = 0; j < 4; ++j) {
                    int row = rowbase + mt * 16 + lq * 4 + j;
                    float keep = 1.f - ms[mt][j];
                    float v = acc3[mt][nt][j] * keep;
                    if (hasemb) v = fmaf(e[nt], ms[mt][j], v);
                    feat[(size_t)row * 3072 + f * 32 + o] = v;
                    lacc[mt][nt][j] += v;
                }
            }
    }

    if (part) {
        float* pp = part + (size_t)blockIdx.y * LOGN;
        #pragma unroll
        for (int mt = 0; mt < 2; ++mt)
            #pragma unroll
            for (int nt = 0; nt < 2; ++nt)
                #pragma unroll
                for (int j = 0; j < 4; ++j) {
                    int row = rowbase + mt * 16 + lq * 4 + j;
                    pp[row * 32 + nt * 16 + lr] = lacc[mt][nt][j];
                }
    }
}

// ---------------- categorical features (+ partial logits) ----------------
__global__ __launch_bounds__(256)
void nam_cat(const float* __restrict__ tab, const float* __restrict__ cat_linear,
             const float* __restrict__ memb, float* __restrict__ feat,
             float* __restrict__ part) {
    int t = blockIdx.x * blockDim.x + threadIdx.x;   // 8192*32
    int o = t & 31;
    int b = t >> 5;
    const float* tb = tab + (size_t)b * 192;
    float sum = 0.f;
    #pragma unroll
    for (int fc = 0; fc < 32; ++fc) {
        float val = tb[64 + fc];
        float miss = tb[160 + fc];
        float r = cat_linear[fc * 32 + o] * val * (1.f - miss);
        if (fc < 8) r = fmaf(memb[fc * 32 + o], miss, r);
        feat[(size_t)b * 3072 + (64 + fc) * 32 + o] = r;
        sum += r;
    }
    if (part) part[8 * LOGN + t] = sum;
}

// ---------------- final: sum 9 partial planes + bias ----------------
__global__ __launch_bounds__(256)
void nam_reduce(const float* __restrict__ part, const float* __restrict__ bias,
                float* __restrict__ logits) {
    int t = blockIdx.x * blockDim.x + threadIdx.x;
    float s = bias[t & 31];
    #pragma unroll
    for (int g = 0; g < 9; ++g) s += part[g * LOGN + t];
    logits[t] = s;
}

// ---------------- fallback logits (if ws too small for partials) ----------------
__global__ __launch_bounds__(256)
void nam_logits(const float* __restrict__ feat, const float* __restrict__ bias,
                float* __restrict__ logits) {
    int t = blockIdx.x * blockDim.x + threadIdx.x;
    int o = t & 31;
    int b = t >> 5;
    float s = bias[o];
    const float* fp = feat + (size_t)b * 3072 + o;
    #pragma unroll 8
    for (int f = 0; f < 96; ++f) s += fp[f * 32];
    logits[t] = s;
}

extern "C" void kernel_launch(void* const* d_in, const int* in_sizes, int n_in,
                              void* d_out, int out_size, void* d_ws, size_t ws_size,
                              hipStream_t stream) {
    const float* tab        = (const float*)d_in[0];
    const float* v0         = (const float*)d_in[1];
    const float* g0         = (const float*)d_in[2];
    const float* b0         = (const float*)d_in[3];
    const float* v1         = (const float*)d_in[4];
    const float* g1         = (const float*)d_in[5];
    const float* b1         = (const float*)d_in[6];
    const float* v2         = (const float*)d_in[7];
    const float* g2         = (const float*)d_in[8];
    const float* b2         = (const float*)d_in[9];
    const float* v3         = (const float*)d_in[10];
    const float* g3         = (const float*)d_in[11];
    const float* cat_linear = (const float*)d_in[12];
    const float* memb       = (const float*)d_in[13];
    const float* bias       = (const float*)d_in[14];

    float* out    = (float*)d_out;
    float* logits = out;                 // [8192][32]
    float* feat   = out + LOGN;          // [8192][96][32]

    float* w0  = (float*)d_ws;
    f16*   b1f = (f16*)((char*)d_ws + OFF_B1);
    f16*   b2f = (f16*)((char*)d_ws + OFF_B2);
    f16*   b3f = (f16*)((char*)d_ws + OFF_B3);
    float* part = (float*)((char*)d_ws + OFF_PART);
    const bool use_part = ws_size >= (size_t)OFF_PART + 9ull * LOGN * 4ull;
    float* partp = use_part ? part : nullptr;

    prep_weights<<<48, 256, 0, stream>>>(v0, g0, v1, g1, v2, g2, v3, g3, w0, b1f, b2f, b3f);

    dim3 gr(64, 8);
    nam_real_mfma<<<gr, 256, 0, stream>>>(tab, w0, b1f, b2f, b3f, b0, b1, b2, memb, feat, partp);

    nam_cat<<<LOGN / 256, 256, 0, stream>>>(tab, cat_linear, memb, feat, partp);

    if (use_part)
        nam_reduce<<<LOGN / 256, 256, 0, stream>>>(part, bias, logits);
    else
        nam_logits<<<LOGN / 256, 256, 0, stream>>>(feat, bias, logits);
}

// Round 3
// 48.001 us; speedup vs baseline: 4.3271x; 1.1051x over previous
//
#include <hip/hip_runtime.h>
#include <math.h>

typedef _Float16 f16;
typedef _Float16 f16x8 __attribute__((ext_vector_type(8)));
typedef float f32x4 __attribute__((ext_vector_type(4)));

#define NB 8192
#define LOGN (NB * 32)          // 262144 logits elements

// ---- ws byte layout ----
#define OFF_W0   0              // 4096 f32 (= g0 * sign(v0))
#define OFF_SC1  16384          // 4096 f32 scales for v1 rows
#define OFF_SC2  32768          // 2048 f32
#define OFF_SC3  40960          // 2048 f32
#define OFF_B1   49152          // 262144 f16 fragments [f][ks2][nt4][lane64][8]
#define OFF_B2   573440         // 131072 f16 [f][ks2][nt2][lane][8]
#define OFF_B3   835584         // 65536 f16 [f][nt2][lane][8]
#define OFF_PART 966656         // 8 planes of [8192][32] f32 partial logits
#define WS_NEED  (OFF_PART + 8ull * LOGN * 4ull)

// ---------------- prep 1: norms/scales ----------------
__global__ __launch_bounds__(256)
void prep_norm(const float* __restrict__ v0, const float* __restrict__ g0,
               const float* __restrict__ v1, const float* __restrict__ g1,
               const float* __restrict__ v2, const float* __restrict__ g2,
               const float* __restrict__ v3, const float* __restrict__ g3,
               float* __restrict__ ws) {
    int t = blockIdx.x * blockDim.x + threadIdx.x;
    if (t < 4096) {
        float v = v0[t];
        ws[OFF_W0 / 4 + t] = g0[t] * (v >= 0.f ? 1.f : -1.f);
    } else if (t < 8192) {
        int r = t - 4096;
        const float* vp = v1 + (size_t)r * 64;
        float ss = 0.f;
        #pragma unroll
        for (int i = 0; i < 16; ++i) {
            float4 x = *(const float4*)(vp + i * 4);
            ss += x.x * x.x + x.y * x.y + x.z * x.z + x.w * x.w;
        }
        ws[OFF_SC1 / 4 + r] = g1[r] * __frsqrt_rn(ss);
    } else if (t < 10240) {
        int r = t - 8192;
        const float* vp = v2 + (size_t)r * 64;
        float ss = 0.f;
        #pragma unroll
        for (int i = 0; i < 16; ++i) {
            float4 x = *(const float4*)(vp + i * 4);
            ss += x.x * x.x + x.y * x.y + x.z * x.z + x.w * x.w;
        }
        ws[OFF_SC2 / 4 + r] = g2[r] * __frsqrt_rn(ss);
    } else if (t < 12288) {
        int r = t - 10240;
        const float* vp = v3 + (size_t)r * 32;
        float ss = 0.f;
        #pragma unroll
        for (int i = 0; i < 8; ++i) {
            float4 x = *(const float4*)(vp + i * 4);
            ss += x.x * x.x + x.y * x.y + x.z * x.z + x.w * x.w;
        }
        ws[OFF_SC3 / 4 + r] = g3[r] * __frsqrt_rn(ss);
    }
}

// ---------------- prep 2: scatter weight-normed fp16 fragments (coalesced stores) ----------------
__global__ __launch_bounds__(256)
void prep_frag(const float* __restrict__ v1, const float* __restrict__ v2,
               const float* __restrict__ v3, const float* __restrict__ ws,
               f16* __restrict__ b1f, f16* __restrict__ b2f, f16* __restrict__ b3f) {
    int t = blockIdx.x * blockDim.x + threadIdx.x;   // 458752 total
    if (t < 262144) {
        // b1f[t]: t = f*4096 + ks*2048 + nt*512 + lane*8 + i
        int i = t & 7, lane = (t >> 3) & 63, nt = (t >> 9) & 3, ks = (t >> 11) & 1, f = t >> 12;
        int k = ks * 32 + ((lane >> 4) << 3) + i;
        int n = nt * 16 + (lane & 15);
        int r = f * 64 + n;
        b1f[t] = (f16)(v1[(size_t)r * 64 + k] * ws[OFF_SC1 / 4 + r]);
    } else if (t < 393216) {
        int t2 = t - 262144;
        int i = t2 & 7, lane = (t2 >> 3) & 63, nt = (t2 >> 9) & 1, ks = (t2 >> 10) & 1, f = t2 >> 11;
        int k = ks * 32 + ((lane >> 4) << 3) + i;
        int n = nt * 16 + (lane & 15);
        int r = f * 32 + n;
        b2f[t2] = (f16)(v2[(size_t)r * 64 + k] * ws[OFF_SC2 / 4 + r]);
    } else {
        int t3 = t - 393216;
        int i = t3 & 7, lane = (t3 >> 3) & 63, nt = (t3 >> 9) & 1, f = t3 >> 10;
        int k = ((lane >> 4) << 3) + i;
        int n = nt * 16 + (lane & 15);
        int r = f * 32 + n;
        b3f[t3] = (f16)(v3[(size_t)r * 32 + k] * ws[OFF_SC3 / 4 + r]);
    }
}

// ---------------- real features: MFMA MLP chain ----------------
// grid (64 batch-tiles, 8 feature-groups) x 256 thr. Wave-private: 32 rows/wave, 8 features.
__global__ __launch_bounds__(256, 2)
void nam_real_mfma(const float* __restrict__ tab, const float* __restrict__ w0,
                   const f16* __restrict__ b1f, const f16* __restrict__ b2f,
                   const f16* __restrict__ b3f,
                   const float* __restrict__ b0, const float* __restrict__ b1,
                   const float* __restrict__ b2, const float* __restrict__ memb,
                   float* __restrict__ feat, float* __restrict__ part) {
    __shared__ char lds[4][8192];           // per-wave h1/h2 staging
    __shared__ float tv[128][8];            // tab values for this block's 8 features
    __shared__ float tm[128][8];            // tab missing flags
    const int wave = threadIdx.x >> 6, lane = threadIdx.x & 63;
    const int lq = lane >> 4, lr = lane & 15;
    const int rowbase = blockIdx.x * 128 + wave * 32;
    const int f0 = blockIdx.y * 8;
    char* h1b = lds[wave];
    char* h2b = lds[wave] + 4096;

    // ---- coalesced tab staging: 128 rows x (8 val + 8 miss) ----
    #pragma unroll
    for (int it = 0; it < 8; ++it) {
        int g = it * 256 + threadIdx.x;     // 0..2047
        int row = g >> 4, w = g & 15;
        int col = (w < 8) ? (f0 + w) : (96 + f0 + (w - 8));
        float x = tab[(size_t)(blockIdx.x * 128 + row) * 192 + col];
        if (w < 8) tv[row][w] = x; else tm[row][w - 8] = x;
    }
    __syncthreads();

    float lacc[2][2][4];
    #pragma unroll
    for (int mt = 0; mt < 2; ++mt)
        #pragma unroll
        for (int nt = 0; nt < 2; ++nt)
            #pragma unroll
            for (int j = 0; j < 4; ++j) lacc[mt][nt][j] = 0.f;

    #pragma unroll 1
    for (int fi = 0; fi < 8; ++fi) {
        const int f = f0 + fi;

        // ---- B fragments (coalesced 16B/lane, L2-resident) ----
        f16x8 B1[2][4], B2[2][2], B3[2];
        {
            const f16* p1 = b1f + f * 4096 + lane * 8;
            #pragma unroll
            for (int ks = 0; ks < 2; ++ks)
                #pragma unroll
                for (int nt = 0; nt < 4; ++nt)
                    B1[ks][nt] = *(const f16x8*)(p1 + ks * 2048 + nt * 512);
            const f16* p2 = b2f + f * 2048 + lane * 8;
            #pragma unroll
            for (int ks = 0; ks < 2; ++ks)
                #pragma unroll
                for (int nt = 0; nt < 2; ++nt)
                    B2[ks][nt] = *(const f16x8*)(p2 + ks * 1024 + nt * 512);
            const f16* p3 = b3f + f * 1024 + lane * 8;
            #pragma unroll
            for (int nt = 0; nt < 2; ++nt)
                B3[nt] = *(const f16x8*)(p3 + nt * 512);
        }

        // ---- biases / per-row inputs (from LDS) ----
        float b1v[4], b2v[2];
        #pragma unroll
        for (int nt = 0; nt < 4; ++nt) b1v[nt] = b1[f * 64 + nt * 16 + lr];
        #pragma unroll
        for (int nt = 0; nt < 2; ++nt) b2v[nt] = b2[f * 32 + nt * 16 + lr];
        float vmt[2];
        #pragma unroll
        for (int mt = 0; mt < 2; ++mt)
            vmt[mt] = tv[wave * 32 + mt * 16 + lr][fi];
        float ms[2][4];
        #pragma unroll
        for (int mt = 0; mt < 2; ++mt)
            #pragma unroll
            for (int j = 0; j < 4; ++j)
                ms[mt][j] = tm[wave * 32 + mt * 16 + lq * 4 + j][fi];

        // ---- layer 0: build A fragments in registers (w0 = +/- g0) ----
        f16x8 A0[2][2];
        #pragma unroll
        for (int ks = 0; ks < 2; ++ks) {
            float w0v[8], b0v[8];
            *(float4*)&w0v[0] = *(const float4*)(w0 + f * 64 + ks * 32 + lq * 8);
            *(float4*)&w0v[4] = *(const float4*)(w0 + f * 64 + ks * 32 + lq * 8 + 4);
            *(float4*)&b0v[0] = *(const float4*)(b0 + f * 64 + ks * 32 + lq * 8);
            *(float4*)&b0v[4] = *(const float4*)(b0 + f * 64 + ks * 32 + lq * 8 + 4);
            #pragma unroll
            for (int mt = 0; mt < 2; ++mt)
                #pragma unroll
                for (int i = 0; i < 8; ++i)
                    A0[mt][ks][i] = (f16)fmaxf(fmaf(vmt[mt], w0v[i], b0v[i]), 0.f);
        }

        // ---- layer 1: [32x64] = A0[32x64] * W1^T ----
        f32x4 acc1[2][4];
        #pragma unroll
        for (int mt = 0; mt < 2; ++mt)
            #pragma unroll
            for (int nt = 0; nt < 4; ++nt) acc1[mt][nt] = (f32x4){0.f, 0.f, 0.f, 0.f};
        #pragma unroll
        for (int ks = 0; ks < 2; ++ks)
            #pragma unroll
            for (int nt = 0; nt < 4; ++nt)
                #pragma unroll
                for (int mt = 0; mt < 2; ++mt)
                    acc1[mt][nt] = __builtin_amdgcn_mfma_f32_16x16x32_f16(A0[mt][ks], B1[ks][nt], acc1[mt][nt], 0, 0, 0);
        // relu+bias -> fp16 -> swizzled LDS
        #pragma unroll
        for (int mt = 0; mt < 2; ++mt)
            #pragma unroll
            for (int nt = 0; nt < 4; ++nt) {
                int n = nt * 16 + lr;
                int colb = ((n >> 3) << 4) + ((n & 7) << 1);
                #pragma unroll
                for (int j = 0; j < 4; ++j) {
                    int row = mt * 16 + lq * 4 + j;
                    int byte = ((row << 7) + colb) ^ ((row & 7) << 4);
                    *(f16*)(h1b + byte) = (f16)fmaxf(acc1[mt][nt][j] + b1v[nt], 0.f);
                }
            }

        // ---- layer 2: [32x32] = H1[32x64] * W2^T ----
        f16x8 A1[2][2];
        #pragma unroll
        for (int mt = 0; mt < 2; ++mt)
            #pragma unroll
            for (int ks = 0; ks < 2; ++ks) {
                int row = mt * 16 + lr;
                int byte = ((row << 7) + ((ks * 4 + lq) << 4)) ^ ((row & 7) << 4);
                A1[mt][ks] = *(const f16x8*)(h1b + byte);
            }
        f32x4 acc2[2][2];
        #pragma unroll
        for (int mt = 0; mt < 2; ++mt)
            #pragma unroll
            for (int nt = 0; nt < 2; ++nt) acc2[mt][nt] = (f32x4){0.f, 0.f, 0.f, 0.f};
        #pragma unroll
        for (int ks = 0; ks < 2; ++ks)
            #pragma unroll
            for (int nt = 0; nt < 2; ++nt)
                #pragma unroll
                for (int mt = 0; mt < 2; ++mt)
                    acc2[mt][nt] = __builtin_amdgcn_mfma_f32_16x16x32_f16(A1[mt][ks], B2[ks][nt], acc2[mt][nt], 0, 0, 0);
        #pragma unroll
        for (int mt = 0; mt < 2; ++mt)
            #pragma unroll
            for (int nt = 0; nt < 2; ++nt) {
                int n = nt * 16 + lr;
                int colb = ((n >> 3) << 4) + ((n & 7) << 1);
                #pragma unroll
                for (int j = 0; j < 4; ++j) {
                    int row = mt * 16 + lq * 4 + j;
                    int byte = ((row << 7) + colb) ^ ((row & 7) << 4);
                    *(f16*)(h2b + byte) = (f16)fmaxf(acc2[mt][nt][j] + b2v[nt], 0.f);
                }
            }

        // ---- layer 3: [32x32] = H2[32x32] * W3^T ----
        f16x8 A2[2];
        #pragma unroll
        for (int mt = 0; mt < 2; ++mt) {
            int row = mt * 16 + lr;
            int byte = ((row << 7) + (lq << 4)) ^ ((row & 7) << 4);
            A2[mt] = *(const f16x8*)(h2b + byte);
        }
        f32x4 acc3[2][2];
        #pragma unroll
        for (int mt = 0; mt < 2; ++mt)
            #pragma unroll
            for (int nt = 0; nt < 2; ++nt) acc3[mt][nt] = (f32x4){0.f, 0.f, 0.f, 0.f};
        #pragma unroll
        for (int nt = 0; nt < 2; ++nt)
            #pragma unroll
            for (int mt = 0; mt < 2; ++mt)
                acc3[mt][nt] = __builtin_amdgcn_mfma_f32_16x16x32_f16(A2[mt], B3[nt], acc3[mt][nt], 0, 0, 0);

        // ---- epilogue: mask, missing-emb, store, logits partial ----
        float e[2] = {0.f, 0.f};
        const bool hasemb = (f < 16);
        if (hasemb) {
            #pragma unroll
            for (int nt = 0; nt < 2; ++nt) e[nt] = memb[(8 + f) * 32 + nt * 16 + lr];
        }
        #pragma unroll
        for (int mt = 0; mt < 2; ++mt)
            #pragma unroll
            for (int nt = 0; nt < 2; ++nt) {
                int o = nt * 16 + lr;
                #pragma unroll
                for (int j = 0; j < 4; ++j) {
                    int row = rowbase + mt * 16 + lq * 4 + j;
                    float keep = 1.f - ms[mt][j];
                    float v = acc3[mt][nt][j] * keep;
                    if (hasemb) v = fmaf(e[nt], ms[mt][j], v);
                    feat[(size_t)row * 3072 + f * 32 + o] = v;
                    lacc[mt][nt][j] += v;
                }
            }
    }

    if (part) {
        float* pp = part + (size_t)blockIdx.y * LOGN;
        #pragma unroll
        for (int mt = 0; mt < 2; ++mt)
            #pragma unroll
            for (int nt = 0; nt < 2; ++nt)
                #pragma unroll
                for (int j = 0; j < 4; ++j) {
                    int row = rowbase + mt * 16 + lq * 4 + j;
                    pp[row * 32 + nt * 16 + lr] = lacc[mt][nt][j];
                }
    }
}

// ---------------- categorical features + final logits (fused) ----------------
__global__ __launch_bounds__(256)
void nam_cat_reduce(const float* __restrict__ tab, const float* __restrict__ cat_linear,
                    const float* __restrict__ memb, const float* __restrict__ bias,
                    const float* __restrict__ part, float* __restrict__ feat,
                    float* __restrict__ logits) {
    int t = blockIdx.x * blockDim.x + threadIdx.x;   // 8192*32
    int o = t & 31;
    int b = t >> 5;
    const float* tb = tab + (size_t)b * 192;
    float s = bias[o];
    if (part) {
        #pragma unroll
        for (int g = 0; g < 8; ++g) s += part[g * LOGN + t];
    }
    #pragma unroll
    for (int fc = 0; fc < 32; ++fc) {
        float val = tb[64 + fc];
        float miss = tb[160 + fc];
        float r = cat_linear[fc * 32 + o] * val * (1.f - miss);
        if (fc < 8) r = fmaf(memb[fc * 32 + o], miss, r);
        feat[(size_t)b * 3072 + (64 + fc) * 32 + o] = r;
        s += r;
    }
    if (part) logits[t] = s;
}

// ---------------- fallback logits (if ws too small for partials) ----------------
__global__ __launch_bounds__(256)
void nam_logits(const float* __restrict__ feat, const float* __restrict__ bias,
                float* __restrict__ logits) {
    int t = blockIdx.x * blockDim.x + threadIdx.x;
    int o = t & 31;
    int b = t >> 5;
    float s = bias[o];
    const float* fp = feat + (size_t)b * 3072 + o;
    #pragma unroll 8
    for (int f = 0; f < 96; ++f) s += fp[f * 32];
    logits[t] = s;
}

extern "C" void kernel_launch(void* const* d_in, const int* in_sizes, int n_in,
                              void* d_out, int out_size, void* d_ws, size_t ws_size,
                              hipStream_t stream) {
    const float* tab        = (const float*)d_in[0];
    const float* v0         = (const float*)d_in[1];
    const float* g0         = (const float*)d_in[2];
    const float* b0         = (const float*)d_in[3];
    const float* v1         = (const float*)d_in[4];
    const float* g1         = (const float*)d_in[5];
    const float* b1         = (const float*)d_in[6];
    const float* v2         = (const float*)d_in[7];
    const float* g2         = (const float*)d_in[8];
    const float* b2         = (const float*)d_in[9];
    const float* v3         = (const float*)d_in[10];
    const float* g3         = (const float*)d_in[11];
    const float* cat_linear = (const float*)d_in[12];
    const float* memb       = (const float*)d_in[13];
    const float* bias       = (const float*)d_in[14];

    float* out    = (float*)d_out;
    float* logits = out;                 // [8192][32]
    float* feat   = out + LOGN;          // [8192][96][32]

    float* ws   = (float*)d_ws;
    float* w0   = (float*)((char*)d_ws + OFF_W0);
    f16*   b1f  = (f16*)((char*)d_ws + OFF_B1);
    f16*   b2f  = (f16*)((char*)d_ws + OFF_B2);
    f16*   b3f  = (f16*)((char*)d_ws + OFF_B3);
    float* part = (float*)((char*)d_ws + OFF_PART);
    const bool use_part = ws_size >= WS_NEED;
    float* partp = use_part ? part : nullptr;

    prep_norm<<<48, 256, 0, stream>>>(v0, g0, v1, g1, v2, g2, v3, g3, ws);
    prep_frag<<<1792, 256, 0, stream>>>(v1, v2, v3, ws, b1f, b2f, b3f);

    dim3 gr(64, 8);
    nam_real_mfma<<<gr, 256, 0, stream>>>(tab, w0, b1f, b2f, b3f, b0, b1, b2, memb, feat, partp);

    nam_cat_reduce<<<LOGN / 256, 256, 0, stream>>>(tab, cat_linear, memb, bias, partp, feat, logits);

    if (!use_part)
        nam_logits<<<LOGN / 256, 256, 0, stream>>>(feat, bias, logits);
}